// Round 3
// baseline (5993.553 us; speedup 1.0000x reference)
//
#include <hip/hip_runtime.h>
#include <math.h>

// Problem constants (B=2, T=2048, C=1024, H=16, D=64)
#define Bn 2
#define Tn 2048
#define Cn 1024
#define Hn 16
#define Dn 64

// ---------------------------------------------------------------------------
// GEMM: C[M,N] = A[M,K] @ B[K,N] + bias[N]   (fp32, 64x64 tile, 256 threads)
// (unchanged from round 0 — ~73 TF fp32; attention is the current bottleneck)
// ---------------------------------------------------------------------------
__global__ __launch_bounds__(256) void gemm_bias(const float* __restrict__ A,
                                                 const float* __restrict__ B,
                                                 const float* __restrict__ bias,
                                                 float* __restrict__ C,
                                                 int M, int N, int K) {
    __shared__ float As[16][68];   // As[k][m], stride 68 floats = 272B == 0 mod 16
    __shared__ float Bs[16][68];   // Bs[k][n]

    const int tid = threadIdx.x;
    const int tx = tid & 15;       // n
    const int ty = tid >> 4;       // m
    const int m0 = blockIdx.y * 64;
    const int n0 = blockIdx.x * 64;

    float acc[4][4] = {};

    for (int k0 = 0; k0 < K; k0 += 16) {
        {
            int row = tid >> 2;
            int cg  = (tid & 3) << 2;
            float4 a = *(const float4*)(A + (size_t)(m0 + row) * K + k0 + cg);
            As[cg + 0][row] = a.x;
            As[cg + 1][row] = a.y;
            As[cg + 2][row] = a.z;
            As[cg + 3][row] = a.w;
        }
        {
            int row = tid >> 4;
            int cg  = (tid & 15) << 2;
            *(float4*)(&Bs[row][cg]) =
                *(const float4*)(B + (size_t)(k0 + row) * N + n0 + cg);
        }
        __syncthreads();

        #pragma unroll
        for (int kk = 0; kk < 16; ++kk) {
            float4 a4 = *(const float4*)(&As[kk][ty << 2]);
            float4 b4 = *(const float4*)(&Bs[kk][tx << 2]);
            float av[4] = {a4.x, a4.y, a4.z, a4.w};
            float bv[4] = {b4.x, b4.y, b4.z, b4.w};
            #pragma unroll
            for (int i = 0; i < 4; ++i)
                #pragma unroll
                for (int j = 0; j < 4; ++j)
                    acc[i][j] += av[i] * bv[j];
        }
        __syncthreads();
    }

    const int c0 = n0 + (tx << 2);
    float4 bb = *(const float4*)(bias + c0);
    #pragma unroll
    for (int i = 0; i < 4; ++i) {
        int row = m0 + (ty << 2) + i;
        float4 o;
        o.x = acc[i][0] + bb.x;
        o.y = acc[i][1] + bb.y;
        o.z = acc[i][2] + bb.z;
        o.w = acc[i][3] + bb.w;
        *(float4*)(C + (size_t)row * N + c0) = o;
    }
}

// ---------------------------------------------------------------------------
// Flash attention v2 (causal, fp32): 4-way D-split, 16 queries per wave.
// lane = di*16 + qi: lane owns dims [di*16, di*16+16) of query row q0+qi.
// QK^T dot = 16 lane-local FMAs + shfl_xor(16) + shfl_xor(32).
// Softmax state (m, l) replicated across the 4 D-quarters (identical values).
// No LDS, no barriers: K/V rows broadcast-loaded from global (L2-resident,
// XCD-swizzled so one XCD's resident heads fit its 4 MB L2).
// 4096 waves total (4x round-0), ~80 VGPR -> deep occupancy for latency hiding.
// ---------------------------------------------------------------------------
template<bool MASKED>
__device__ __forceinline__ void attn_group(const float* __restrict__ kp0,
                                           const float* __restrict__ vp0,
                                           int kg, int q,
                                           const float* __restrict__ Q,
                                           float* __restrict__ O,
                                           float& m, float& l) {
    const float scale = 0.125f;  // 1/sqrt(64)
    float s[8];
    float mt = -INFINITY;
    #pragma unroll
    for (int kk = 0; kk < 8; ++kk) {
        const float* kp = kp0 + (size_t)(kg + kk) * (3 * Cn);
        float sp = 0.f;
        #pragma unroll
        for (int j = 0; j < 16; j += 4) {
            float4 t = *(const float4*)(kp + j);
            sp += Q[j] * t.x;
            sp += Q[j + 1] * t.y;
            sp += Q[j + 2] * t.z;
            sp += Q[j + 3] * t.w;
        }
        sp += __shfl_xor(sp, 16);
        sp += __shfl_xor(sp, 32);
        sp *= scale;
        if (MASKED) sp = ((kg + kk) <= q) ? sp : -INFINITY;
        s[kk] = sp;
        mt = fmaxf(mt, sp);
    }
    const float mnew = fmaxf(m, mt);
    const float corr = __expf(m - mnew);   // 0 when m == -inf (mnew finite)
    l *= corr;
    #pragma unroll
    for (int j = 0; j < 16; ++j) O[j] *= corr;
    #pragma unroll
    for (int kk = 0; kk < 8; ++kk) {
        const float pr = __expf(s[kk] - mnew);  // 0 for masked keys
        l += pr;
        const float* vp = vp0 + (size_t)(kg + kk) * (3 * Cn);
        #pragma unroll
        for (int j = 0; j < 16; j += 4) {
            float4 t = *(const float4*)(vp + j);
            O[j]     += pr * t.x;
            O[j + 1] += pr * t.y;
            O[j + 2] += pr * t.z;
            O[j + 3] += pr * t.w;
        }
    }
    m = mnew;
}

__global__ __launch_bounds__(256, 8) void attn_flash2(const float* __restrict__ qkv,
                                                      float* __restrict__ y) {
    const int lane = threadIdx.x & 63;
    const int qi   = lane & 15;          // query within wave
    const int di   = lane >> 4;          // D-quarter 0..3

    // XCD-aware work mapping: 1024 blocks; block -> (b,h) such that all blocks
    // of one head share blockIdx % 8 (same XCD under round-robin dispatch).
    // Within a head, chunks are ordered largest-first (most keys first).
    const int bid = blockIdx.x;          // 0..1023
    const int xcd = bid & 7;
    const int idx = bid >> 3;            // 0..127
    const int p   = xcd + 8 * (idx >> 5);        // (b*H+h) id, 0..31
    const int blk_in_head = idx & 31;            // 0..31
    const int cw  = blk_in_head * 4 + (threadIdx.x >> 6);  // 0..127
    const int c   = 127 - cw;                    // chunk: largest first
    const int b   = p >> 4;
    const int h   = p & 15;

    const int q0 = c * 16;
    const int q  = q0 + qi;              // this lane's query row

    const float* base  = qkv + (size_t)b * (Tn * 3 * Cn);
    const float* kbase = base + Cn + h * Dn + di * 16;       // + k*3072
    const float* vbase = base + 2 * Cn + h * Dn + di * 16;

    // Q quarter -> registers
    float Q[16];
    {
        const float* qp = base + (size_t)q * (3 * Cn) + h * Dn + di * 16;
        #pragma unroll
        for (int j = 0; j < 16; j += 4) {
            float4 t = *(const float4*)(qp + j);
            Q[j] = t.x; Q[j + 1] = t.y; Q[j + 2] = t.z; Q[j + 3] = t.w;
        }
    }

    float m = -INFINITY, l = 0.f;
    float O[16];
    #pragma unroll
    for (int j = 0; j < 16; ++j) O[j] = 0.f;

    // Main loop: keys [0, q0) — fully unmasked for all 16 queries of the wave.
    for (int kg = 0; kg < q0; kg += 8)
        attn_group<false>(kbase, vbase, kg, q, Q, O, m, l);
    // Diagonal tail: keys [q0, q0+16) with causal mask.
    attn_group<true>(kbase, vbase, q0, q, Q, O, m, l);
    attn_group<true>(kbase, vbase, q0 + 8, q, Q, O, m, l);

    // Epilogue: normalize, store this lane's quarter.
    const float inv = 1.f / l;
    float* yp = y + (size_t)(b * Tn + q) * Cn + h * Dn + di * 16;
    #pragma unroll
    for (int j = 0; j < 16; j += 4) {
        float4 t;
        t.x = O[j] * inv; t.y = O[j + 1] * inv;
        t.z = O[j + 2] * inv; t.w = O[j + 3] * inv;
        *(float4*)(yp + j) = t;
    }
}

// ---------------------------------------------------------------------------
extern "C" void kernel_launch(void* const* d_in, const int* in_sizes, int n_in,
                              void* d_out, int out_size, void* d_ws, size_t ws_size,
                              hipStream_t stream) {
    const float* x    = (const float*)d_in[0];  // [B,T,C]
    const float* Wqkv = (const float*)d_in[1];  // [C,3C]
    const float* bqkv = (const float*)d_in[2];  // [3C]
    const float* Wo   = (const float*)d_in[3];  // [C,C]
    const float* bo   = (const float*)d_in[4];  // [C]
    float* out = (float*)d_out;                 // [B,T,C] fp32

    const int M = Bn * Tn;                            // 4096
    float* qkv = (float*)d_ws;                        // [4096, 3072] = 48 MB
    float* yat = qkv + (size_t)M * (3 * Cn);          // [4096, 1024] = 16 MB

    // 1) qkv = x @ Wqkv + bqkv
    {
        dim3 grid((3 * Cn) / 64, M / 64), blk(256);
        gemm_bias<<<grid, blk, 0, stream>>>(x, Wqkv, bqkv, qkv, M, 3 * Cn, Cn);
    }
    // 2) causal flash attention: 1024 blocks x 4 independent waves,
    //    16 queries per wave, 4-way D-split.
    {
        dim3 grid(1024), blk(256);
        attn_flash2<<<grid, blk, 0, stream>>>(qkv, yat);
    }
    // 3) out = yat @ Wo + bo
    {
        dim3 grid(Cn / 64, M / 64), blk(256);
        gemm_bias<<<grid, blk, 0, stream>>>(yat, Wo, bo, out, M, Cn, Cn);
    }
}

// Round 8
// 2556.778 us; speedup vs baseline: 2.3442x; 2.3442x over previous
//
#include <hip/hip_runtime.h>
#include <math.h>

// Problem constants (B=2, T=2048, C=1024, H=16, D=64)
#define Bn 2
#define Tn 2048
#define Cn 1024
#define Hn 16
#define Dn 64

typedef short  bf16x8 __attribute__((ext_vector_type(8)));  // 8 bf16 (4 VGPRs)
typedef short  s16x4  __attribute__((ext_vector_type(4)));  // 8-byte LDS store
typedef float  f32x4  __attribute__((ext_vector_type(4)));  // MFMA accumulator

// fp32 -> bf16 round-to-nearest-even (bit ops; values are tame, no NaN care)
static __device__ __forceinline__ unsigned short f32_bf16(float f) {
    unsigned u = __float_as_uint(f);
    return (unsigned short)((u + 0x7fffu + ((u >> 16) & 1u)) >> 16);
}
static __device__ __forceinline__ float bf16_f32(unsigned short h) {
    return __uint_as_float(((unsigned)h) << 16);
}

// ---------------------------------------------------------------------------
// MFMA GEMM with bf16 hi/lo split: C = A@B + bias, A[M,K], B[K,N] fp32.
// Each fp32 a = ah + al (two bf16, al = rne(a - ah)); product uses 3 MFMAs:
// ah*bh + ah*bl + al*bh (dropped al*bl ~ 2^-16 rel -> fp32-grade result).
//
// 128x128 block, 4 waves (2x2), each wave 64x64 = 4x4 fragments of 16x16x32.
// A/B k-slot map: lane l supplies k = (l>>4)*8 + i, i=0..7 — any SHARED
// bijection between A and B operands is self-consistent (HW pairs by true k;
// a consistent permutation cancels). C/D map (HW-verified): col = lane&15,
// row = (lane>>4)*4 + reg.
// LDS: A stored [row][k] (frag read = 1 ds_read_b128), B stored TRANSPOSED
// [n][k] via in-wave 4x4 shuffle transpose at staging time.
// Row stride 40 shorts = 80 B (16B-aligned rows; ~2-way bank aliasing, free).
// ---------------------------------------------------------------------------
__global__ __launch_bounds__(256) void gemm_mfma3(const float* __restrict__ A,
                                                  const float* __restrict__ B,
                                                  const float* __restrict__ bias,
                                                  float* __restrict__ C,
                                                  int M, int N, int K) {
    __shared__ short Ah[128][40];
    __shared__ short Al[128][40];
    __shared__ short Bh[128][40];   // transposed: Bh[n][k]
    __shared__ short Bl[128][40];

    const int tid = threadIdx.x;
    const int m0 = blockIdx.y * 128;
    const int n0 = blockIdx.x * 128;
    const int w  = tid >> 6;             // wave 0..3
    const int l  = tid & 63;
    const int wr = w >> 1;               // wave row 0..1  (64 rows each)
    const int wc = w & 1;                // wave col 0..1  (64 cols each)
    const int lr = l & 15;
    const int g8 = (l >> 4) * 8;         // k-chunk of this lane's fragments

    // staging maps
    const int a_in  = tid & 7;           // A: col = 4*a_in
    const int a_r0  = tid >> 3;          // A: row = a_r0 + 32*c4
    const int q     = tid >> 2;          // B: quad id 0..63
    const int e     = tid & 3;           // B: lane in quad
    const int b_n   = 4 * (q & 31);      // B: n-chunk base (block-relative)
    const int b_kb  = 16 * (q >> 5);     // B: k-half base

    f32x4 acc[4][4];
    #pragma unroll
    for (int i = 0; i < 4; ++i)
        #pragma unroll
        for (int j = 0; j < 4; ++j)
            acc[i][j] = (f32x4){0.f, 0.f, 0.f, 0.f};

    for (int k0 = 0; k0 < K; k0 += 32) {
        // ---- stage A: 128x32 fp32 -> Ah/Al [row][k] ----
        #pragma unroll
        for (int c4 = 0; c4 < 4; ++c4) {
            const int row = a_r0 + 32 * c4;
            const float4 v = *(const float4*)(A + (size_t)(m0 + row) * K + k0 + 4 * a_in);
            unsigned short h0 = f32_bf16(v.x), h1 = f32_bf16(v.y),
                           h2 = f32_bf16(v.z), h3 = f32_bf16(v.w);
            s16x4 hv = {(short)h0, (short)h1, (short)h2, (short)h3};
            s16x4 lv = {(short)f32_bf16(v.x - bf16_f32(h0)),
                        (short)f32_bf16(v.y - bf16_f32(h1)),
                        (short)f32_bf16(v.z - bf16_f32(h2)),
                        (short)f32_bf16(v.w - bf16_f32(h3))};
            *(s16x4*)&Ah[row][4 * a_in] = hv;   // 80*row + 8*a_in: 8B-aligned
            *(s16x4*)&Al[row][4 * a_in] = lv;
        }
        // ---- stage B: 32x128 fp32 -> Bh/Bl [n][k] via quad 4x4 transpose ----
        #pragma unroll
        for (int c = 0; c < 4; ++c) {
            const int krow = b_kb + 4 * c + e;   // this lane loads row krow
            const float4 v = *(const float4*)(B + (size_t)(k0 + krow) * N + n0 + b_n);
            // 4x4 transpose across quad (verified):
            // stage1 (xor 1): u[e even]=(v.x,b.x,v.z,b.z), u[e odd]=(b.y,v.y,b.w,v.w)
            float4 b1, u, b2, t;
            b1.x = __shfl_xor(v.x, 1); b1.y = __shfl_xor(v.y, 1);
            b1.z = __shfl_xor(v.z, 1); b1.w = __shfl_xor(v.w, 1);
            if (e & 1) { u.x = b1.y; u.y = v.y; u.z = b1.w; u.w = v.w; }
            else       { u.x = v.x;  u.y = b1.x; u.z = v.z; u.w = b1.z; }
            b2.x = __shfl_xor(u.x, 2); b2.y = __shfl_xor(u.y, 2);
            b2.z = __shfl_xor(u.z, 2); b2.w = __shfl_xor(u.w, 2);
            if (e & 2) { t.x = b2.z; t.y = b2.w; t.z = u.z; t.w = u.w; }
            else       { t.x = u.x;  t.y = u.y;  t.z = b2.x; t.w = b2.y; }
            // t = B[k0 + b_kb+4c .. +3][n0 + b_n + e]  (column, 4 consecutive k)
            const int nrow = b_n + e;
            const int kcol = b_kb + 4 * c;
            unsigned short h0 = f32_bf16(t.x), h1 = f32_bf16(t.y),
                           h2 = f32_bf16(t.z), h3 = f32_bf16(t.w);
            s16x4 hv = {(short)h0, (short)h1, (short)h2, (short)h3};
            s16x4 lv = {(short)f32_bf16(t.x - bf16_f32(h0)),
                        (short)f32_bf16(t.y - bf16_f32(h1)),
                        (short)f32_bf16(t.z - bf16_f32(h2)),
                        (short)f32_bf16(t.w - bf16_f32(h3))};
            *(s16x4*)&Bh[nrow][kcol] = hv;
            *(s16x4*)&Bl[nrow][kcol] = lv;
        }
        __syncthreads();

        // ---- fragments: one ds_read_b128 each (16B-aligned: 80r + 2*g8) ----
        bf16x8 fah[4], fal[4], fbh[4], fbl[4];
        #pragma unroll
        for (int i = 0; i < 4; ++i) {
            fah[i] = *(const bf16x8*)&Ah[64 * wr + 16 * i + lr][g8];
            fal[i] = *(const bf16x8*)&Al[64 * wr + 16 * i + lr][g8];
            fbh[i] = *(const bf16x8*)&Bh[64 * wc + 16 * i + lr][g8];
            fbl[i] = *(const bf16x8*)&Bl[64 * wc + 16 * i + lr][g8];
        }
        #pragma unroll
        for (int i = 0; i < 4; ++i)
            #pragma unroll
            for (int j = 0; j < 4; ++j) {
                acc[i][j] = __builtin_amdgcn_mfma_f32_16x16x32_bf16(fah[i], fbh[j], acc[i][j], 0, 0, 0);
                acc[i][j] = __builtin_amdgcn_mfma_f32_16x16x32_bf16(fah[i], fbl[j], acc[i][j], 0, 0, 0);
                acc[i][j] = __builtin_amdgcn_mfma_f32_16x16x32_bf16(fal[i], fbh[j], acc[i][j], 0, 0, 0);
            }
        __syncthreads();
    }

    // ---- epilogue: D[row][col], col = lane&15, row = (lane>>4)*4 + reg ----
    #pragma unroll
    for (int j = 0; j < 4; ++j) {
        const int col = n0 + 64 * wc + 16 * j + lr;
        const float bv = bias[col];
        #pragma unroll
        for (int i = 0; i < 4; ++i) {
            const int rbase = m0 + 64 * wr + 16 * i + (l >> 4) * 4;
            #pragma unroll
            for (int r = 0; r < 4; ++r)
                C[(size_t)(rbase + r) * N + col] = acc[i][j][r] + bv;
        }
    }
}

// ---------------------------------------------------------------------------
// Flash attention v2 (causal, fp32): 4-way D-split, 16 queries per wave.
// ROUND-3 LESSON: (256,8) capped VGPR at 64 -> allocator chose 32 -> arrays
// spilled -> 4.2 GB scratch writes (matched WRITE_SIZE). (256,4) caps at 128.
// ---------------------------------------------------------------------------
template<bool MASKED>
__device__ __forceinline__ void attn_group(const float* __restrict__ kp0,
                                           const float* __restrict__ vp0,
                                           int kg, int q,
                                           const float* __restrict__ Q,
                                           float* __restrict__ O,
                                           float& m, float& l) {
    const float scale = 0.125f;  // 1/sqrt(64)
    float s[8];
    float mt = -INFINITY;
    #pragma unroll
    for (int kk = 0; kk < 8; ++kk) {
        const float* kp = kp0 + (size_t)(kg + kk) * (3 * Cn);
        float sp = 0.f;
        #pragma unroll
        for (int j = 0; j < 16; j += 4) {
            float4 t = *(const float4*)(kp + j);
            sp += Q[j] * t.x;
            sp += Q[j + 1] * t.y;
            sp += Q[j + 2] * t.z;
            sp += Q[j + 3] * t.w;
        }
        sp += __shfl_xor(sp, 16);
        sp += __shfl_xor(sp, 32);
        sp *= scale;
        if (MASKED) sp = ((kg + kk) <= q) ? sp : -INFINITY;
        s[kk] = sp;
        mt = fmaxf(mt, sp);
    }
    const float mnew = fmaxf(m, mt);
    const float corr = __expf(m - mnew);   // 0 when m == -inf (mnew finite)
    l *= corr;
    #pragma unroll
    for (int j = 0; j < 16; ++j) O[j] *= corr;
    #pragma unroll
    for (int kk = 0; kk < 8; ++kk) {
        const float pr = __expf(s[kk] - mnew);  // 0 for masked keys
        l += pr;
        const float* vp = vp0 + (size_t)(kg + kk) * (3 * Cn);
        #pragma unroll
        for (int j = 0; j < 16; j += 4) {
            float4 t = *(const float4*)(vp + j);
            O[j]     += pr * t.x;
            O[j + 1] += pr * t.y;
            O[j + 2] += pr * t.z;
            O[j + 3] += pr * t.w;
        }
    }
    m = mnew;
}

__global__ __launch_bounds__(256, 4) void attn_flash2(const float* __restrict__ qkv,
                                                      float* __restrict__ y) {
    const int lane = threadIdx.x & 63;
    const int qi   = lane & 15;          // query within wave
    const int di   = lane >> 4;          // D-quarter 0..3

    // XCD-aware map: all blocks of one head share blockIdx%8 (same XCD under
    // round-robin); chunks largest-first within a head.
    const int bid = blockIdx.x;          // 0..1023
    const int xcd = bid & 7;
    const int idx = bid >> 3;            // 0..127
    const int p   = xcd + 8 * (idx >> 5);        // (b*H+h) id, 0..31
    const int blk_in_head = idx & 31;            // 0..31
    const int cw  = blk_in_head * 4 + (threadIdx.x >> 6);  // 0..127
    const int c   = 127 - cw;                    // chunk: largest first
    const int b   = p >> 4;
    const int h   = p & 15;

    const int q0 = c * 16;
    const int q  = q0 + qi;              // this lane's query row

    const float* base  = qkv + (size_t)b * (Tn * 3 * Cn);
    const float* kbase = base + Cn + h * Dn + di * 16;       // + k*3072
    const float* vbase = base + 2 * Cn + h * Dn + di * 16;

    float Q[16];
    {
        const float* qp = base + (size_t)q * (3 * Cn) + h * Dn + di * 16;
        #pragma unroll
        for (int j = 0; j < 16; j += 4) {
            float4 t = *(const float4*)(qp + j);
            Q[j] = t.x; Q[j + 1] = t.y; Q[j + 2] = t.z; Q[j + 3] = t.w;
        }
    }

    float m = -INFINITY, l = 0.f;
    float O[16];
    #pragma unroll
    for (int j = 0; j < 16; ++j) O[j] = 0.f;

    for (int kg = 0; kg < q0; kg += 8)
        attn_group<false>(kbase, vbase, kg, q, Q, O, m, l);
    attn_group<true>(kbase, vbase, q0, q, Q, O, m, l);
    attn_group<true>(kbase, vbase, q0 + 8, q, Q, O, m, l);

    const float inv = 1.f / l;
    float* yp = y + (size_t)(b * Tn + q) * Cn + h * Dn + di * 16;
    #pragma unroll
    for (int j = 0; j < 16; j += 4) {
        float4 t;
        t.x = O[j] * inv; t.y = O[j + 1] * inv;
        t.z = O[j + 2] * inv; t.w = O[j + 3] * inv;
        *(float4*)(yp + j) = t;
    }
}

// ---------------------------------------------------------------------------
extern "C" void kernel_launch(void* const* d_in, const int* in_sizes, int n_in,
                              void* d_out, int out_size, void* d_ws, size_t ws_size,
                              hipStream_t stream) {
    const float* x    = (const float*)d_in[0];  // [B,T,C]
    const float* Wqkv = (const float*)d_in[1];  // [C,3C]
    const float* bqkv = (const float*)d_in[2];  // [3C]
    const float* Wo   = (const float*)d_in[3];  // [C,C]
    const float* bo   = (const float*)d_in[4];  // [C]
    float* out = (float*)d_out;                 // [B,T,C] fp32

    const int M = Bn * Tn;                            // 4096
    float* qkv = (float*)d_ws;                        // [4096, 3072] = 48 MB
    float* yat = qkv + (size_t)M * (3 * Cn);          // [4096, 1024] = 16 MB

    // 1) qkv = x @ Wqkv + bqkv   (MFMA bf16x3)
    {
        dim3 grid((3 * Cn) / 128, M / 128), blk(256);
        gemm_mfma3<<<grid, blk, 0, stream>>>(x, Wqkv, bqkv, qkv, M, 3 * Cn, Cn);
    }
    // 2) causal flash attention: 1024 blocks x 4 waves, 16 queries/wave
    {
        dim3 grid(1024), blk(256);
        attn_flash2<<<grid, blk, 0, stream>>>(qkv, yat);
    }
    // 3) out = yat @ Wo + bo   (MFMA bf16x3)
    {
        dim3 grid(Cn / 128, M / 128), blk(256);
        gemm_mfma3<<<grid, blk, 0, stream>>>(yat, Wo, bo, out, M, Cn, Cn);
    }
}

// Round 10
// 423.965 us; speedup vs baseline: 14.1369x; 6.0306x over previous
//
#include <hip/hip_runtime.h>
#include <math.h>

// Problem constants (B=2, T=2048, C=1024, H=16, D=64)
#define Bn 2
#define Tn 2048
#define Cn 1024
#define Hn 16
#define Dn 64

typedef short  bf16x8 __attribute__((ext_vector_type(8)));  // 8 bf16 (4 VGPRs)
typedef short  s16x4  __attribute__((ext_vector_type(4)));  // 8-byte LDS store
typedef float  f32x4  __attribute__((ext_vector_type(4)));  // MFMA accumulator

// fp32 -> bf16 round-to-nearest-even
static __device__ __forceinline__ unsigned short f32_bf16(float f) {
    unsigned u = __float_as_uint(f);
    return (unsigned short)((u + 0x7fffu + ((u >> 16) & 1u)) >> 16);
}
static __device__ __forceinline__ float bf16_f32(unsigned short h) {
    return __uint_as_float(((unsigned)h) << 16);
}
// split fp32x4 into hi/lo bf16x4 pair and store to LDS (8B each)
static __device__ __forceinline__ void split_store(short* dh, short* dl, float4 v) {
    unsigned short h0 = f32_bf16(v.x), h1 = f32_bf16(v.y),
                   h2 = f32_bf16(v.z), h3 = f32_bf16(v.w);
    *(s16x4*)dh = (s16x4){(short)h0, (short)h1, (short)h2, (short)h3};
    *(s16x4*)dl = (s16x4){(short)f32_bf16(v.x - bf16_f32(h0)),
                          (short)f32_bf16(v.y - bf16_f32(h1)),
                          (short)f32_bf16(v.z - bf16_f32(h2)),
                          (short)f32_bf16(v.w - bf16_f32(h3))};
}

// ---------------------------------------------------------------------------
// MFMA GEMM, bf16 hi/lo x3 — HW-VERIFIED round 8 (absmax 3.9e-3 passed).
// Unchanged.
// ---------------------------------------------------------------------------
__global__ __launch_bounds__(256) void gemm_mfma3(const float* __restrict__ A,
                                                  const float* __restrict__ B,
                                                  const float* __restrict__ bias,
                                                  float* __restrict__ C,
                                                  int M, int N, int K) {
    __shared__ short Ah[128][40];
    __shared__ short Al[128][40];
    __shared__ short Bh[128][40];   // transposed: Bh[n][k]
    __shared__ short Bl[128][40];

    const int tid = threadIdx.x;
    const int m0 = blockIdx.y * 128;
    const int n0 = blockIdx.x * 128;
    const int w  = tid >> 6;
    const int l  = tid & 63;
    const int wr = w >> 1;
    const int wc = w & 1;
    const int lr = l & 15;
    const int g8 = (l >> 4) * 8;

    const int a_in  = tid & 7;
    const int a_r0  = tid >> 3;
    const int q     = tid >> 2;
    const int e     = tid & 3;
    const int b_n   = 4 * (q & 31);
    const int b_kb  = 16 * (q >> 5);

    f32x4 acc[4][4];
    #pragma unroll
    for (int i = 0; i < 4; ++i)
        #pragma unroll
        for (int j = 0; j < 4; ++j)
            acc[i][j] = (f32x4){0.f, 0.f, 0.f, 0.f};

    for (int k0 = 0; k0 < K; k0 += 32) {
        #pragma unroll
        for (int c4 = 0; c4 < 4; ++c4) {
            const int row = a_r0 + 32 * c4;
            const float4 v = *(const float4*)(A + (size_t)(m0 + row) * K + k0 + 4 * a_in);
            split_store(&Ah[row][4 * a_in], &Al[row][4 * a_in], v);
        }
        #pragma unroll
        for (int c = 0; c < 4; ++c) {
            const int krow = b_kb + 4 * c + e;
            const float4 v = *(const float4*)(B + (size_t)(k0 + krow) * N + n0 + b_n);
            float4 b1, u, b2, t;
            b1.x = __shfl_xor(v.x, 1); b1.y = __shfl_xor(v.y, 1);
            b1.z = __shfl_xor(v.z, 1); b1.w = __shfl_xor(v.w, 1);
            if (e & 1) { u.x = b1.y; u.y = v.y; u.z = b1.w; u.w = v.w; }
            else       { u.x = v.x;  u.y = b1.x; u.z = v.z; u.w = b1.z; }
            b2.x = __shfl_xor(u.x, 2); b2.y = __shfl_xor(u.y, 2);
            b2.z = __shfl_xor(u.z, 2); b2.w = __shfl_xor(u.w, 2);
            if (e & 2) { t.x = b2.z; t.y = b2.w; t.z = u.z; t.w = u.w; }
            else       { t.x = u.x;  t.y = u.y;  t.z = b2.x; t.w = b2.y; }
            const int nrow = b_n + e;
            const int kcol = b_kb + 4 * c;
            split_store(&Bh[nrow][kcol], &Bl[nrow][kcol], t);
        }
        __syncthreads();

        bf16x8 fah[4], fal[4], fbh[4], fbl[4];
        #pragma unroll
        for (int i = 0; i < 4; ++i) {
            fah[i] = *(const bf16x8*)&Ah[64 * wr + 16 * i + lr][g8];
            fal[i] = *(const bf16x8*)&Al[64 * wr + 16 * i + lr][g8];
            fbh[i] = *(const bf16x8*)&Bh[64 * wc + 16 * i + lr][g8];
            fbl[i] = *(const bf16x8*)&Bl[64 * wc + 16 * i + lr][g8];
        }
        #pragma unroll
        for (int i = 0; i < 4; ++i)
            #pragma unroll
            for (int j = 0; j < 4; ++j) {
                acc[i][j] = __builtin_amdgcn_mfma_f32_16x16x32_bf16(fah[i], fbh[j], acc[i][j], 0, 0, 0);
                acc[i][j] = __builtin_amdgcn_mfma_f32_16x16x32_bf16(fah[i], fbl[j], acc[i][j], 0, 0, 0);
                acc[i][j] = __builtin_amdgcn_mfma_f32_16x16x32_bf16(fal[i], fbh[j], acc[i][j], 0, 0, 0);
            }
        __syncthreads();
    }

    #pragma unroll
    for (int j = 0; j < 4; ++j) {
        const int col = n0 + 64 * wc + 16 * j + lr;
        const float bv = bias[col];
        #pragma unroll
        for (int i = 0; i < 4; ++i) {
            const int rbase = m0 + 64 * wr + 16 * i + (l >> 4) * 4;
            #pragma unroll
            for (int r = 0; r < 4; ++r)
                C[(size_t)(rbase + r) * N + col] = acc[i][j][r] + bv;
        }
    }
}

// ---------------------------------------------------------------------------
// MFMA flash attention (causal), fp32-grade via bf16 hi/lo 3-term.
// Block = 64 q-rows of one (b,h); 4 waves x 16 q-rows. kv-tiles of 64 keys.
//
// Fragment conventions = gemm_mfma3 (HW-verified round 8):
//   A/B-frag: row/col = lane&15, k-slot = (lane>>4)*8 + i (+32 per chunk)
//   C/D:      col = lane&15, row = (lane>>4)*4 + reg
// QK^T: A=Q rows q, B=K^T cols k -> B-frag reads K_lds[k][d]: K staged in
// NATURAL [k][d] layout (no transpose). PV: B=V[k][d] -> B-frag needs
// Vt[d][k]: staged via the verified quad 4x4 shuffle transpose.
// P round-trip: acc (col=k,row=q) -> LDS [q][k] -> A-frag (row=q=lane&15);
// wave-private region, wave-synchronous LDS (in-order per-wave ds ops).
// Row stride 72 shorts = 144 B (16B-aligned frags; r,r+8 2-way bank = free).
// LDS 54 KB -> 2 blocks/CU. Softmax row-reduce: 4x shfl_xor in 16-lane group.
// ---------------------------------------------------------------------------
__global__ __launch_bounds__(256) void attn_mfma(const float* __restrict__ qkv,
                                                 float* __restrict__ y) {
    __shared__ short K_h[64][72], K_l[64][72];     // Q at start, then K: [row][d]
    __shared__ short V_h[64][72], V_l[64][72];     // transposed V: [d][k]
    __shared__ short P_h[4][16][72], P_l[4][16][72];

    const int tid = threadIdx.x;
    const int w   = tid >> 6;        // wave 0..3 -> q rows [16w, 16w+16)
    const int ln  = tid & 63;
    const int g   = ln >> 4;         // 0..3
    const int c16 = ln & 15;

    // bid -> (b,h,qt): consecutive bids = different heads (spread over XCDs,
    // head's K/V stays on one XCD: bid%8 const for fixed p); largest qt first.
    const int bid = blockIdx.x;      // 0..1023
    const int p   = bid & 31;
    const int qt  = 31 - (bid >> 5); // 31..0
    const int b   = p >> 4;
    const int h   = p & 15;

    const float* base = qkv + (size_t)b * (Tn * 3 * Cn) + h * Dn;

    // ---- stage Q tile (64 x 64) into K_h/K_l, hoist frags to registers ----
    {
        const int r  = tid >> 2;
        const int c4 = 4 * (tid & 3);
        #pragma unroll
        for (int c = 0; c < 4; ++c) {
            const int col = c4 + 16 * c;
            const float4 v = *(const float4*)(base + (size_t)(64 * qt + r) * (3 * Cn) + col);
            split_store(&K_h[r][col], &K_l[r][col], v);
        }
    }
    __syncthreads();
    bf16x8 qh[2], ql[2];
    qh[0] = *(const bf16x8*)&K_h[16 * w + c16][8 * g];
    qh[1] = *(const bf16x8*)&K_h[16 * w + c16][32 + 8 * g];
    ql[0] = *(const bf16x8*)&K_l[16 * w + c16][8 * g];
    ql[1] = *(const bf16x8*)&K_l[16 * w + c16][32 + 8 * g];
    __syncthreads();

    f32x4 Y[4];
    #pragma unroll
    for (int j = 0; j < 4; ++j) Y[j] = (f32x4){0.f, 0.f, 0.f, 0.f};
    float m[4]    = {-INFINITY, -INFINITY, -INFINITY, -INFINITY};
    float lsum[4] = {0.f, 0.f, 0.f, 0.f};

    for (int kt = 0; kt <= qt; ++kt) {
        // ---- stage K tile [k][d] (natural layout) ----
        {
            const int r  = tid >> 2;
            const int c4 = 4 * (tid & 3);
            #pragma unroll
            for (int c = 0; c < 4; ++c) {
                const int col = c4 + 16 * c;
                const float4 v = *(const float4*)(base + Cn + (size_t)(64 * kt + r) * (3 * Cn) + col);
                split_store(&K_h[r][col], &K_l[r][col], v);
            }
        }
        // ---- stage V transposed [d][k] via quad 4x4 transpose ----
        {
            const int q2 = tid >> 2, e = tid & 3;
            const int kb = 4 * (q2 & 15);     // k-quad base
            const int db = 16 * (q2 >> 4);    // d-superblock
            #pragma unroll
            for (int c = 0; c < 4; ++c) {
                const int d4 = db + 4 * c;
                const float4 v = *(const float4*)(base + 2 * Cn + (size_t)(64 * kt + kb + e) * (3 * Cn) + d4);
                float4 b1, u, b2, t;
                b1.x = __shfl_xor(v.x, 1); b1.y = __shfl_xor(v.y, 1);
                b1.z = __shfl_xor(v.z, 1); b1.w = __shfl_xor(v.w, 1);
                if (e & 1) { u.x = b1.y; u.y = v.y; u.z = b1.w; u.w = v.w; }
                else       { u.x = v.x;  u.y = b1.x; u.z = v.z; u.w = b1.z; }
                b2.x = __shfl_xor(u.x, 2); b2.y = __shfl_xor(u.y, 2);
                b2.z = __shfl_xor(u.z, 2); b2.w = __shfl_xor(u.w, 2);
                if (e & 2) { t.x = b2.z; t.y = b2.w; t.z = u.z; t.w = u.w; }
                else       { t.x = u.x;  t.y = u.y;  t.z = b2.x; t.w = b2.y; }
                // t = V[k = kb..kb+3][d4 + e] -> Vt row d4+e, cols kb..kb+3
                split_store(&V_h[d4 + e][kb], &V_l[d4 + e][kb], t);
            }
        }
        __syncthreads();

        // ---- QK^T: S[16q x 64k] per wave, 6 MFMAs per 16k tile ----
        f32x4 sa[4];
        #pragma unroll
        for (int t = 0; t < 4; ++t) sa[t] = (f32x4){0.f, 0.f, 0.f, 0.f};
        #pragma unroll
        for (int t = 0; t < 4; ++t) {
            const bf16x8 kh0 = *(const bf16x8*)&K_h[16 * t + c16][8 * g];
            const bf16x8 kh1 = *(const bf16x8*)&K_h[16 * t + c16][32 + 8 * g];
            const bf16x8 kl0 = *(const bf16x8*)&K_l[16 * t + c16][8 * g];
            const bf16x8 kl1 = *(const bf16x8*)&K_l[16 * t + c16][32 + 8 * g];
            sa[t] = __builtin_amdgcn_mfma_f32_16x16x32_bf16(qh[0], kh0, sa[t], 0, 0, 0);
            sa[t] = __builtin_amdgcn_mfma_f32_16x16x32_bf16(qh[1], kh1, sa[t], 0, 0, 0);
            sa[t] = __builtin_amdgcn_mfma_f32_16x16x32_bf16(qh[0], kl0, sa[t], 0, 0, 0);
            sa[t] = __builtin_amdgcn_mfma_f32_16x16x32_bf16(qh[1], kl1, sa[t], 0, 0, 0);
            sa[t] = __builtin_amdgcn_mfma_f32_16x16x32_bf16(ql[0], kh0, sa[t], 0, 0, 0);
            sa[t] = __builtin_amdgcn_mfma_f32_16x16x32_bf16(ql[1], kh1, sa[t], 0, 0, 0);
        }

        // ---- online softmax in acc layout (col k = c16, row q = 4g+r) ----
        const bool diag = (kt == qt);
        float sc[4][4];
        #pragma unroll
        for (int t = 0; t < 4; ++t)
            #pragma unroll
            for (int r = 0; r < 4; ++r) {
                float v = sa[t][r] * 0.125f;   // 1/sqrt(64)
                if (diag && (16 * t + c16 > 16 * w + 4 * g + r)) v = -INFINITY;
                sc[t][r] = v;
            }
        #pragma unroll
        for (int r = 0; r < 4; ++r) {
            float mt = fmaxf(fmaxf(sc[0][r], sc[1][r]), fmaxf(sc[2][r], sc[3][r]));
            mt = fmaxf(mt, __shfl_xor(mt, 1));
            mt = fmaxf(mt, __shfl_xor(mt, 2));
            mt = fmaxf(mt, __shfl_xor(mt, 4));
            mt = fmaxf(mt, __shfl_xor(mt, 8));
            const float mnew = fmaxf(m[r], mt);          // finite (diag incl. k=q)
            const float corr = __expf(m[r] - mnew);      // 0 on first tile
            m[r] = mnew;
            float rs = 0.f;
            #pragma unroll
            for (int t = 0; t < 4; ++t) {
                const float pe = __expf(sc[t][r] - mnew);  // 0 for masked
                sc[t][r] = pe;
                rs += pe;
            }
            rs += __shfl_xor(rs, 1);
            rs += __shfl_xor(rs, 2);
            rs += __shfl_xor(rs, 4);
            rs += __shfl_xor(rs, 8);
            lsum[r] = lsum[r] * corr + rs;
            #pragma unroll
            for (int j = 0; j < 4; ++j) Y[j][r] *= corr;
        }

        // ---- P -> LDS (hi/lo), wave-private region ----
        #pragma unroll
        for (int t = 0; t < 4; ++t)
            #pragma unroll
            for (int r = 0; r < 4; ++r) {
                const unsigned short ph = f32_bf16(sc[t][r]);
                const unsigned short pl = f32_bf16(sc[t][r] - bf16_f32(ph));
                P_h[w][4 * g + r][16 * t + c16] = (short)ph;
                P_l[w][4 * g + r][16 * t + c16] = (short)pl;
            }

        // ---- PV: Y[16q x 64d] += P[16q x 64k] @ V[64k x 64d] ----
        bf16x8 pfh[2], pfl[2];
        pfh[0] = *(const bf16x8*)&P_h[w][c16][8 * g];
        pfh[1] = *(const bf16x8*)&P_h[w][c16][32 + 8 * g];
        pfl[0] = *(const bf16x8*)&P_l[w][c16][8 * g];
        pfl[1] = *(const bf16x8*)&P_l[w][c16][32 + 8 * g];
        #pragma unroll
        for (int j = 0; j < 4; ++j) {
            #pragma unroll
            for (int kc = 0; kc < 2; ++kc) {
                const bf16x8 vh = *(const bf16x8*)&V_h[16 * j + c16][32 * kc + 8 * g];
                const bf16x8 vl = *(const bf16x8*)&V_l[16 * j + c16][32 * kc + 8 * g];
                Y[j] = __builtin_amdgcn_mfma_f32_16x16x32_bf16(pfh[kc], vh, Y[j], 0, 0, 0);
                Y[j] = __builtin_amdgcn_mfma_f32_16x16x32_bf16(pfh[kc], vl, Y[j], 0, 0, 0);
                Y[j] = __builtin_amdgcn_mfma_f32_16x16x32_bf16(pfl[kc], vh, Y[j], 0, 0, 0);
            }
        }
        __syncthreads();
    }

    // ---- epilogue: normalize, store (D map: row q = 4g+r, col d = 16j+c16) ----
    float* yb = y + (size_t)(b * Tn + 64 * qt) * Cn + h * Dn;
    #pragma unroll
    for (int r = 0; r < 4; ++r) {
        const float inv = 1.f / lsum[r];
        #pragma unroll
        for (int j = 0; j < 4; ++j)
            yb[(size_t)(16 * w + 4 * g + r) * Cn + 16 * j + c16] = Y[j][r] * inv;
    }
}

// ---------------------------------------------------------------------------
extern "C" void kernel_launch(void* const* d_in, const int* in_sizes, int n_in,
                              void* d_out, int out_size, void* d_ws, size_t ws_size,
                              hipStream_t stream) {
    const float* x    = (const float*)d_in[0];  // [B,T,C]
    const float* Wqkv = (const float*)d_in[1];  // [C,3C]
    const float* bqkv = (const float*)d_in[2];  // [3C]
    const float* Wo   = (const float*)d_in[3];  // [C,C]
    const float* bo   = (const float*)d_in[4];  // [C]
    float* out = (float*)d_out;                 // [B,T,C] fp32

    const int M = Bn * Tn;                            // 4096
    float* qkv = (float*)d_ws;                        // [4096, 3072] = 48 MB
    float* yat = qkv + (size_t)M * (3 * Cn);          // [4096, 1024] = 16 MB

    // 1) qkv = x @ Wqkv + bqkv   (MFMA bf16x3)
    {
        dim3 grid((3 * Cn) / 128, M / 128), blk(256);
        gemm_mfma3<<<grid, blk, 0, stream>>>(x, Wqkv, bqkv, qkv, M, 3 * Cn, Cn);
    }
    // 2) causal MFMA flash attention: 1024 blocks (b,h,q-tile), 4 waves each
    {
        dim3 grid(1024), blk(256);
        attn_mfma<<<grid, blk, 0, stream>>>(qkv, yat);
    }
    // 3) out = yat @ Wo + bo   (MFMA bf16x3)
    {
        dim3 grid(Cn / 128, M / 128), blk(256);
        gemm_mfma3<<<grid, blk, 0, stream>>>(yat, Wo, bo, out, M, Cn, Cn);
    }
}